// Round 1
// baseline (126.649 us; speedup 1.0000x reference)
//
#include <hip/hip_runtime.h>
#include <hip/hip_bf16.h>

typedef __attribute__((ext_vector_type(8))) short bf16x8;
typedef __attribute__((ext_vector_type(4))) float f32x4;

#define LOG2E 1.4426950408889634f

static __device__ __forceinline__ short f2bf(float f) {
    return (short)__builtin_bit_cast(unsigned short, __float2bfloat16(f));
}

// ---------------- projection: x[16384,1024] @ [Wq|Wk|Wv][1024,192] ------------
// Writes Q (scaled by 1/32), K as [B*T][64] bf16, V transposed as [B][64][T] bf16.
__global__ __launch_bounds__(256) void proj_kernel(
    const float* __restrict__ x,
    const float* __restrict__ Wq, const float* __restrict__ Wk, const float* __restrict__ Wv,
    unsigned short* __restrict__ Qb, unsigned short* __restrict__ Kb, unsigned short* __restrict__ Vt)
{
    __shared__ float sA[64][36];    // 64 rows x 32 k, pad 36 -> 2-way conflicts max
    __shared__ float sB[32][194];   // 32 k x 192 n, pad 194 -> 2-way conflicts max

    const int tid  = threadIdx.x;
    const int lane = tid & 63;
    const int w    = tid >> 6;      // wave id (0..3), owns rows 16w..16w+15
    const int r    = lane & 15;
    const int g    = lane >> 4;
    const int mbase = blockIdx.x * 64;

    f32x4 acc[12];
#pragma unroll
    for (int i = 0; i < 12; ++i) acc[i] = (f32x4)0.0f;

    const int arow = tid >> 2;          // A staging: 4 threads/row, 8 floats each
    const int acb  = (tid & 3) * 8;

    for (int kb = 0; kb < 1024; kb += 32) {
        // ---- stage A tile (64x32 fp32), coalesced ----
        {
            const float* src = x + (size_t)(mbase + arow) * 1024 + kb + acb;
            float4 v0 = *reinterpret_cast<const float4*>(src);
            float4 v1 = *reinterpret_cast<const float4*>(src + 4);
            *reinterpret_cast<float4*>(&sA[arow][acb])     = v0;
            *reinterpret_cast<float4*>(&sA[arow][acb + 4]) = v1;
        }
        // ---- stage B tile (32x192 fp32): 3072 float2 chunks over 256 threads ----
#pragma unroll
        for (int i = 0; i < 12; ++i) {
            int chunk = tid + 256 * i;
            int k   = chunk / 96;           // 96 float2 per k-row
            int c2  = chunk % 96;
            int mat = c2 >> 5;              // 0:Wq 1:Wk 2:Wv
            int col = (c2 & 31) * 2;
            const float* wp = (mat == 0) ? Wq : ((mat == 1) ? Wk : Wv);
            float2 v = *reinterpret_cast<const float2*>(wp + (size_t)(kb + k) * 64 + col);
            *reinterpret_cast<float2*>(&sB[k][mat * 64 + col]) = v;
        }
        __syncthreads();
        // ---- fragments + MFMA ----
        bf16x8 af;  // A[m][k]: m = lane&15, k = (lane>>4)*8 + j
        {
            const float* ap = &sA[w * 16 + r][g * 8];
#pragma unroll
            for (int j = 0; j < 8; ++j) af[j] = f2bf(ap[j]);
        }
#pragma unroll
        for (int nt = 0; nt < 12; ++nt) {
            bf16x8 bfr; // B[k][n]: n = lane&15, k = (lane>>4)*8 + j
            const int n = nt * 16 + r;
#pragma unroll
            for (int j = 0; j < 8; ++j) bfr[j] = f2bf(sB[g * 8 + j][n]);
            acc[nt] = __builtin_amdgcn_mfma_f32_16x16x32_bf16(af, bfr, acc[nt], 0, 0, 0);
        }
        __syncthreads();
    }

    // ---- epilogue: D row = (lane>>4)*4 + j, col = lane&15 (m89-verified) ----
    const int row0 = mbase + w * 16 + g * 4;
#pragma unroll
    for (int nt = 0; nt < 12; ++nt) {
        const int mat = nt >> 2;
        const int col = (nt & 3) * 16 + r;
#pragma unroll
        for (int j = 0; j < 4; ++j) {
            const int mrow = row0 + j;
            const float v = acc[nt][j];
            if (mat == 0) {
                Qb[(size_t)mrow * 64 + col] = (unsigned short)f2bf(v * 0.03125f); // fold C^-0.5
            } else if (mat == 1) {
                Kb[(size_t)mrow * 64 + col] = (unsigned short)f2bf(v);
            } else {
                const int bb = mrow >> 11;
                const int tt = mrow & 2047;
                Vt[((size_t)bb * 64 + col) * 2048 + tt] = (unsigned short)f2bf(v);
            }
        }
    }
}

// ---------------- causal flash attention: 1 wave per 16 q-rows ---------------
__global__ __launch_bounds__(64) void attn_kernel(
    const unsigned short* __restrict__ Qb, const unsigned short* __restrict__ Kb,
    const unsigned short* __restrict__ Vt, float* __restrict__ out)
{
    __shared__ unsigned short sP[16][40];   // P transpose buffer, padded

    const int lane = threadIdx.x & 63;
    const int r = lane & 15;
    const int g = lane >> 4;
    const int b = blockIdx.y;
    const int qt = (int)gridDim.x - 1 - (int)blockIdx.x;  // longest tiles launch first
    const int qbase = qt * 16;

    const unsigned short* Qbb = Qb + (size_t)b * 2048 * 64;
    const unsigned short* Kbb = Kb + (size_t)b * 2048 * 64;
    const unsigned short* Vtb = Vt + (size_t)b * 64 * 2048;

    bf16x8 qf[2];   // Q A-frags over head halves
#pragma unroll
    for (int h = 0; h < 2; ++h)
        qf[h] = *reinterpret_cast<const bf16x8*>(Qbb + (size_t)(qbase + r) * 64 + h * 32 + g * 8);

    f32x4 o[4];
#pragma unroll
    for (int i = 0; i < 4; ++i) o[i] = (f32x4)0.0f;
    float m[4], lsum[4];
#pragma unroll
    for (int j = 0; j < 4; ++j) { m[j] = -1e30f; lsum[j] = 0.0f; }

    const int lastq = qbase + 15;
    for (int kv0 = 0; kv0 <= lastq; kv0 += 32) {
        // S = Q K^T for 16q x 32kv (scale already folded into Q)
        f32x4 s0 = (f32x4)0.0f, s1 = (f32x4)0.0f;
#pragma unroll
        for (int h = 0; h < 2; ++h) {
            bf16x8 k0 = *reinterpret_cast<const bf16x8*>(Kbb + (size_t)(kv0 + r) * 64 + h * 32 + g * 8);
            bf16x8 k1 = *reinterpret_cast<const bf16x8*>(Kbb + (size_t)(kv0 + 16 + r) * 64 + h * 32 + g * 8);
            s0 = __builtin_amdgcn_mfma_f32_16x16x32_bf16(qf[h], k0, s0, 0, 0, 0);
            s1 = __builtin_amdgcn_mfma_f32_16x16x32_bf16(qf[h], k1, s1, 0, 0, 0);
        }
        // online softmax; rows live in lanes (g) x regs (j), cols across 16 lanes
#pragma unroll
        for (int j = 0; j < 4; ++j) {
            const int q = qbase + g * 4 + j;
            float a0 = (kv0 + r      <= q) ? s0[j] : -1e30f;
            float a1 = (kv0 + 16 + r <= q) ? s1[j] : -1e30f;
            float t = fmaxf(a0, a1);
#pragma unroll
            for (int off = 1; off < 16; off <<= 1) t = fmaxf(t, __shfl_xor(t, off));
            const float mn = fmaxf(m[j], t);
            const float alpha = __builtin_amdgcn_exp2f((m[j] - mn) * LOG2E);
            const float p0 = __builtin_amdgcn_exp2f((a0 - mn) * LOG2E);
            const float p1 = __builtin_amdgcn_exp2f((a1 - mn) * LOG2E);
            float rs = p0 + p1;
#pragma unroll
            for (int off = 1; off < 16; off <<= 1) rs += __shfl_xor(rs, off);
            lsum[j] = lsum[j] * alpha + rs;
            m[j] = mn;
#pragma unroll
            for (int ht = 0; ht < 4; ++ht) o[ht][j] *= alpha;
            sP[g * 4 + j][r]      = (unsigned short)f2bf(p0);
            sP[g * 4 + j][16 + r] = (unsigned short)f2bf(p1);
        }
        __syncthreads();   // single wave: cheap; orders LDS write->read
        const bf16x8 pf = *reinterpret_cast<const bf16x8*>(&sP[r][g * 8]);
#pragma unroll
        for (int ht = 0; ht < 4; ++ht) {
            bf16x8 vf = *reinterpret_cast<const bf16x8*>(Vtb + (size_t)(ht * 16 + r) * 2048 + kv0 + g * 8);
            o[ht] = __builtin_amdgcn_mfma_f32_16x16x32_bf16(pf, vf, o[ht], 0, 0, 0);
        }
        __syncthreads();   // pf fully consumed before next-iter overwrite
    }

    // epilogue: divide by softmax denom, store fp32 coalesced
#pragma unroll
    for (int j = 0; j < 4; ++j) {
        const float inv = 1.0f / lsum[j];
        const int q = qbase + g * 4 + j;
#pragma unroll
        for (int ht = 0; ht < 4; ++ht)
            out[((size_t)b * 2048 + q) * 64 + ht * 16 + r] = o[ht][j] * inv;
    }
}

extern "C" void kernel_launch(void* const* d_in, const int* in_sizes, int n_in,
                              void* d_out, int out_size, void* d_ws, size_t ws_size,
                              hipStream_t stream) {
    const float* x  = (const float*)d_in[0];
    const float* Wq = (const float*)d_in[1];
    const float* Wk = (const float*)d_in[2];
    const float* Wv = (const float*)d_in[3];
    float* out = (float*)d_out;

    unsigned short* Qb = (unsigned short*)d_ws;                  // [8*2048][64] bf16
    unsigned short* Kb = Qb + (size_t)8 * 2048 * 64;             // [8*2048][64] bf16
    unsigned short* Vt = Kb + (size_t)8 * 2048 * 64;             // [8][64][2048] bf16

    hipLaunchKernelGGL(proj_kernel, dim3(256), dim3(256), 0, stream,
                       x, Wq, Wk, Wv, Qb, Kb, Vt);
    hipLaunchKernelGGL(attn_kernel, dim3(128, 8), dim3(64), 0, stream,
                       Qb, Kb, Vt, out);
}

// Round 2
// 91.231 us; speedup vs baseline: 1.3882x; 1.3882x over previous
//
#include <hip/hip_runtime.h>
#include <hip/hip_bf16.h>

typedef __attribute__((ext_vector_type(8))) short bf16x8;
typedef __attribute__((ext_vector_type(4))) float f32x4;
typedef __attribute__((ext_vector_type(4))) int i32x4;

#define LOG2E 1.4426950408889634f

static __device__ __forceinline__ unsigned int f2bfu(float f) {
    return (unsigned int)__builtin_bit_cast(unsigned short, __float2bfloat16(f));
}
static __device__ __forceinline__ unsigned int pack2(float lo, float hi) {
    return (f2bfu(hi) << 16) | f2bfu(lo);
}
static __device__ __forceinline__ short f2bf(float f) {
    return (short)__builtin_bit_cast(unsigned short, __float2bfloat16(f));
}

// ---------------- projection: x[16384,1024] @ [Wq|Wk|Wv][1024,192] ------------
// bf16 LDS staging (B transposed), reg-prefetch double buffer, 1 barrier/step.
// Writes Q (scaled by 1/32), K as [B*T][64] bf16, V transposed as [B][64][T] bf16.
__global__ __launch_bounds__(256) void proj_kernel(
    const float* __restrict__ x,
    const float* __restrict__ Wq, const float* __restrict__ Wk, const float* __restrict__ Wv,
    unsigned short* __restrict__ Qb, unsigned short* __restrict__ Kb, unsigned short* __restrict__ Vt)
{
    __shared__ __align__(16) unsigned short sA[2][64][40];    // [buf][m][k] bf16
    __shared__ __align__(16) unsigned short sB[2][192][40];   // [buf][n][k] bf16 (transposed)

    const int tid  = threadIdx.x;
    const int w    = tid >> 6;
    const int lane = tid & 63;
    const int r    = lane & 15;
    const int g    = lane >> 4;
    const int mbase = blockIdx.x * 64;

    f32x4 acc[12];
#pragma unroll
    for (int i = 0; i < 12; ++i) acc[i] = (f32x4)0.0f;

    const int arow = tid >> 2;          // A staging: 4 threads/row, 8 floats each
    const int acb  = (tid & 3) * 8;
    const int bn   = tid & 63;          // B staging: column n, 8 consecutive k per mat
    const int bk8  = (tid >> 6) * 8;

    const float* wmat0 = Wq; const float* wmat1 = Wk; const float* wmat2 = Wv;
    float4 a0, a1;
    float wvv0[8], wvv1[8], wvv2[8];

    // prefetch kb = 0
    {
        const float* s = x + (size_t)(mbase + arow) * 1024 + acb;
        a0 = *(const float4*)s; a1 = *(const float4*)(s + 4);
#pragma unroll
        for (int kk = 0; kk < 8; ++kk) {
            wvv0[kk] = wmat0[(size_t)(bk8 + kk) * 64 + bn];
            wvv1[kk] = wmat1[(size_t)(bk8 + kk) * 64 + bn];
            wvv2[kk] = wmat2[(size_t)(bk8 + kk) * 64 + bn];
        }
    }

    int cur = 0;
    for (int kb = 0; kb < 1024; kb += 32) {
        // ---- commit staged regs to LDS (bf16, B transposed) ----
        {
            i32x4 pa = {(int)pack2(a0.x, a0.y), (int)pack2(a0.z, a0.w),
                        (int)pack2(a1.x, a1.y), (int)pack2(a1.z, a1.w)};
            *(i32x4*)&sA[cur][arow][acb] = pa;
            i32x4 p0v = {(int)pack2(wvv0[0], wvv0[1]), (int)pack2(wvv0[2], wvv0[3]),
                         (int)pack2(wvv0[4], wvv0[5]), (int)pack2(wvv0[6], wvv0[7])};
            *(i32x4*)&sB[cur][bn][bk8] = p0v;
            i32x4 p1v = {(int)pack2(wvv1[0], wvv1[1]), (int)pack2(wvv1[2], wvv1[3]),
                         (int)pack2(wvv1[4], wvv1[5]), (int)pack2(wvv1[6], wvv1[7])};
            *(i32x4*)&sB[cur][64 + bn][bk8] = p1v;
            i32x4 p2v = {(int)pack2(wvv2[0], wvv2[1]), (int)pack2(wvv2[2], wvv2[3]),
                         (int)pack2(wvv2[4], wvv2[5]), (int)pack2(wvv2[6], wvv2[7])};
            *(i32x4*)&sB[cur][128 + bn][bk8] = p2v;
        }
        __syncthreads();
        // ---- prefetch next K-step (overlaps with MFMA below) ----
        if (kb + 32 < 1024) {
            const float* s = x + (size_t)(mbase + arow) * 1024 + kb + 32 + acb;
            a0 = *(const float4*)s; a1 = *(const float4*)(s + 4);
#pragma unroll
            for (int kk = 0; kk < 8; ++kk) {
                wvv0[kk] = wmat0[(size_t)(kb + 32 + bk8 + kk) * 64 + bn];
                wvv1[kk] = wmat1[(size_t)(kb + 32 + bk8 + kk) * 64 + bn];
                wvv2[kk] = wmat2[(size_t)(kb + 32 + bk8 + kk) * 64 + bn];
            }
        }
        // ---- fragments + MFMA (single ds_read_b128 each) ----
        bf16x8 af = *(const bf16x8*)&sA[cur][w * 16 + r][g * 8];
#pragma unroll
        for (int nt = 0; nt < 12; ++nt) {
            bf16x8 bfr = *(const bf16x8*)&sB[cur][nt * 16 + r][g * 8];
            acc[nt] = __builtin_amdgcn_mfma_f32_16x16x32_bf16(af, bfr, acc[nt], 0, 0, 0);
        }
        cur ^= 1;
    }

    // ---- epilogue: D row = (lane>>4)*4 + j, col = lane&15 ----
    const int row0 = mbase + w * 16 + g * 4;
#pragma unroll
    for (int nt = 0; nt < 12; ++nt) {
        const int mat = nt >> 2;
        const int col = (nt & 3) * 16 + r;
#pragma unroll
        for (int j = 0; j < 4; ++j) {
            const int mrow = row0 + j;
            const float v = acc[nt][j];
            if (mat == 0) {
                Qb[(size_t)mrow * 64 + col] = (unsigned short)f2bf(v * 0.03125f); // fold C^-0.5
            } else if (mat == 1) {
                Kb[(size_t)mrow * 64 + col] = (unsigned short)f2bf(v);
            } else {
                const int bb = mrow >> 11;
                const int tt = mrow & 2047;
                Vt[((size_t)bb * 64 + col) * 2048 + tt] = (unsigned short)f2bf(v);
            }
        }
    }
}

// ---------------- causal flash attention -------------------------------------
// Block = 256 threads = 4 waves, all on the same 16 q-rows; wave w handles kv
// tiles congruent to w (mod 4). Swapped QK^T (S^T = K Q) makes softmax lane-
// local (lane owns q = qbase + r). Partials merged through LDS at the end.
__global__ __launch_bounds__(256, 4) void attn_kernel(
    const unsigned short* __restrict__ Qb, const unsigned short* __restrict__ Kb,
    const unsigned short* __restrict__ Vt, float* __restrict__ out)
{
    __shared__ __align__(16) float sO[4][4][64][4];   // [wave][ht][lane][j]
    __shared__ float sM[4][16], sL[4][16];

    const int tid  = threadIdx.x;
    const int w    = tid >> 6;
    const int lane = tid & 63;
    const int r    = lane & 15;
    const int g    = lane >> 4;
    const int b    = blockIdx.y;
    const int qt   = (int)gridDim.x - 1 - (int)blockIdx.x;  // longest first
    const int qbase = qt * 16;
    const int q     = qbase + r;        // this lane's q-row

    const unsigned short* Qbb = Qb + (size_t)b * 2048 * 64;
    const unsigned short* Kbb = Kb + (size_t)b * 2048 * 64;
    const unsigned short* Vtb = Vt + (size_t)b * 64 * 2048;

    // Q as B-fragment: B[k][n]: n = lane&15 = q, k = g*8+j
    bf16x8 qf0 = *(const bf16x8*)(Qbb + (size_t)q * 64 + g * 8);
    bf16x8 qf1 = *(const bf16x8*)(Qbb + (size_t)q * 64 + 32 + g * 8);

    f32x4 o[4];
#pragma unroll
    for (int i = 0; i < 4; ++i) o[i] = (f32x4)0.0f;
    float m = -1e30f, l = 0.0f;

    const int lastq = qbase + 15;
    for (int kv0 = w * 32; kv0 <= lastq; kv0 += 128) {
        // K as A-fragment: A[m][k]: m = lane&15 = kv_local, k = g*8+j
        bf16x8 ka0 = *(const bf16x8*)(Kbb + (size_t)(kv0 + r) * 64 + g * 8);
        bf16x8 ka1 = *(const bf16x8*)(Kbb + (size_t)(kv0 + r) * 64 + 32 + g * 8);
        bf16x8 kb0 = *(const bf16x8*)(Kbb + (size_t)(kv0 + 16 + r) * 64 + g * 8);
        bf16x8 kb1 = *(const bf16x8*)(Kbb + (size_t)(kv0 + 16 + r) * 64 + 32 + g * 8);
        // V^T as A-fragment for PV (independent: issue early)
        bf16x8 vf0 = *(const bf16x8*)(Vtb + (size_t)(0 * 16 + r) * 2048 + kv0 + g * 8);
        bf16x8 vf1 = *(const bf16x8*)(Vtb + (size_t)(1 * 16 + r) * 2048 + kv0 + g * 8);
        bf16x8 vf2 = *(const bf16x8*)(Vtb + (size_t)(2 * 16 + r) * 2048 + kv0 + g * 8);
        bf16x8 vf3 = *(const bf16x8*)(Vtb + (size_t)(3 * 16 + r) * 2048 + kv0 + g * 8);

        // S^T tiles: s0 rows kv0..kv0+15, s1 rows kv0+16..kv0+31; col = q = r
        f32x4 s0 = (f32x4)0.0f, s1 = (f32x4)0.0f;
        s0 = __builtin_amdgcn_mfma_f32_16x16x32_bf16(ka0, qf0, s0, 0, 0, 0);
        s0 = __builtin_amdgcn_mfma_f32_16x16x32_bf16(ka1, qf1, s0, 0, 0, 0);
        s1 = __builtin_amdgcn_mfma_f32_16x16x32_bf16(kb0, qf0, s1, 0, 0, 0);
        s1 = __builtin_amdgcn_mfma_f32_16x16x32_bf16(kb1, qf1, s1, 0, 0, 0);

        // lane (r,g) holds S^T[kv0 + 4g + j][q] (s0) and S^T[kv0+16+4g+j][q] (s1)
        bool v0j[4], v1j[4];
        float lm = -1e30f;
#pragma unroll
        for (int j = 0; j < 4; ++j) {
            v0j[j] = (kv0 + 4 * g + j) <= q;
            v1j[j] = (kv0 + 16 + 4 * g + j) <= q;
            float a = v0j[j] ? s0[j] : -1e30f;
            float c = v1j[j] ? s1[j] : -1e30f;
            s0[j] = a; s1[j] = c;
            lm = fmaxf(lm, fmaxf(a, c));
        }
        lm = fmaxf(lm, __shfl_xor(lm, 16));
        lm = fmaxf(lm, __shfl_xor(lm, 32));      // now uniform across g for this q
        const float mn = fmaxf(m, lm);
        const float alpha = __builtin_amdgcn_exp2f((m - mn) * LOG2E);
        float p0[4], p1[4], rs = 0.0f;
#pragma unroll
        for (int j = 0; j < 4; ++j) {
            p0[j] = v0j[j] ? __builtin_amdgcn_exp2f((s0[j] - mn) * LOG2E) : 0.0f;
            p1[j] = v1j[j] ? __builtin_amdgcn_exp2f((s1[j] - mn) * LOG2E) : 0.0f;
            rs += p0[j] + p1[j];
        }
        rs += __shfl_xor(rs, 16);
        rs += __shfl_xor(rs, 32);
        l = l * alpha + rs;
        m = mn;
#pragma unroll
        for (int ht = 0; ht < 4; ++ht) o[ht] *= alpha;

        // Build P^T B-fragment: lane (r,g) needs kv offsets 8g..8g+7 for q=r.
        // Source lanes share r: srcA = r + 32*(g&1) (kv 8g..8g+3), srcB = srcA+16.
        // Tile select: g<2 -> s0-derived (kv<16), g>=2 -> s1-derived.
        const unsigned int pk0l = pack2(p0[0], p0[1]);
        const unsigned int pk0h = pack2(p0[2], p0[3]);
        const unsigned int pk1l = pack2(p1[0], p1[1]);
        const unsigned int pk1h = pack2(p1[2], p1[3]);
        const int srcA = r + ((g & 1) << 5);
        const int srcB = srcA + 16;
        const bool thi = g >= 2;
        int x0a = __shfl((int)pk0l, srcA), x1a = __shfl((int)pk1l, srcA);
        int y0a = __shfl((int)pk0h, srcA), y1a = __shfl((int)pk1h, srcA);
        int x0b = __shfl((int)pk0l, srcB), x1b = __shfl((int)pk1l, srcB);
        int y0b = __shfl((int)pk0h, srcB), y1b = __shfl((int)pk1h, srcB);
        i32x4 pw;
        pw[0] = thi ? x1a : x0a;
        pw[1] = thi ? y1a : y0a;
        pw[2] = thi ? x1b : x0b;
        pw[3] = thi ? y1b : y0b;
        bf16x8 pfrag = __builtin_bit_cast(bf16x8, pw);

        // O^T += V^T P^T : D[h_local][q], lane holds h_local = 4g+j, q = r
        o[0] = __builtin_amdgcn_mfma_f32_16x16x32_bf16(vf0, pfrag, o[0], 0, 0, 0);
        o[1] = __builtin_amdgcn_mfma_f32_16x16x32_bf16(vf1, pfrag, o[1], 0, 0, 0);
        o[2] = __builtin_amdgcn_mfma_f32_16x16x32_bf16(vf2, pfrag, o[2], 0, 0, 0);
        o[3] = __builtin_amdgcn_mfma_f32_16x16x32_bf16(vf3, pfrag, o[3], 0, 0, 0);
    }

    // ---- merge the 4 kv-split partials through LDS ----
    if (g == 0) { sM[w][r] = m; sL[w][r] = l; }
#pragma unroll
    for (int ht = 0; ht < 4; ++ht) *(f32x4*)&sO[w][ht][lane][0] = o[ht];
    __syncthreads();

    float M = sM[0][r];
#pragma unroll
    for (int wp = 1; wp < 4; ++wp) M = fmaxf(M, sM[wp][r]);
    float beta[4];
    float L = 0.0f;
#pragma unroll
    for (int wp = 0; wp < 4; ++wp) {
        beta[wp] = __builtin_amdgcn_exp2f((sM[wp][r] - M) * LOG2E);
        L += beta[wp] * sL[wp][r];
    }
    f32x4 av = (f32x4)0.0f;
#pragma unroll
    for (int wp = 0; wp < 4; ++wp) {
        f32x4 t = *(const f32x4*)&sO[wp][w][lane][0];
        av += t * beta[wp];
    }
    const float inv = 1.0f / L;
    // wave w writes head-dim tile ht = w: h = w*16 + 4g + j, 16B store
    *(f32x4*)(out + ((size_t)b * 2048 + q) * 64 + w * 16 + g * 4) = av * inv;
}

extern "C" void kernel_launch(void* const* d_in, const int* in_sizes, int n_in,
                              void* d_out, int out_size, void* d_ws, size_t ws_size,
                              hipStream_t stream) {
    const float* x  = (const float*)d_in[0];
    const float* Wq = (const float*)d_in[1];
    const float* Wk = (const float*)d_in[2];
    const float* Wv = (const float*)d_in[3];
    float* out = (float*)d_out;

    unsigned short* Qb = (unsigned short*)d_ws;                  // [8*2048][64] bf16
    unsigned short* Kb = Qb + (size_t)8 * 2048 * 64;             // [8*2048][64] bf16
    unsigned short* Vt = Kb + (size_t)8 * 2048 * 64;             // [8][64][2048] bf16

    hipLaunchKernelGGL(proj_kernel, dim3(256), dim3(256), 0, stream,
                       x, Wq, Wk, Wv, Qb, Kb, Vt);
    hipLaunchKernelGGL(attn_kernel, dim3(128, 8), dim3(256), 0, stream,
                       Qb, Kb, Vt, out);
}